// Round 2
// baseline (1760.653 us; speedup 1.0000x reference)
//
#include <hip/hip_runtime.h>
#include <hip/hip_bf16.h>

#define F_DIMC 512
#define HIDC   32

// ---------------- Wc = [W1 | W1*fm1 | W1*fm2]  (512 x 96) ----------------
__global__ void k_wc(const float* __restrict__ W1, const float* __restrict__ fm1,
                     const float* __restrict__ fm2, float* __restrict__ Wc) {
    int i = blockIdx.x * blockDim.x + threadIdx.x;
    if (i >= F_DIMC * HIDC) return;
    int k = i / HIDC, j = i % HIDC;
    float w = W1[i];
    float* row = Wc + k * 96;
    row[j]      = w;
    row[32 + j] = w * fm1[k];
    row[64 + j] = w * fm2[k];
}

// ---------------- per-edge: degree counts + weighted degrees (3 views) ----
__global__ void k_count(const int* __restrict__ ei, const float* __restrict__ ew,
                        const float* __restrict__ m1, const float* __restrict__ m2,
                        int* __restrict__ cnt, float* __restrict__ degf, int E) {
    int e = blockIdx.x * blockDim.x + threadIdx.x;
    if (e >= E) return;
    int d = ei[E + e];
    atomicAdd(&cnt[d], 1);
    float w = ew[e];
    unsafeAtomicAdd(&degf[d * 4 + 0], w);
    unsafeAtomicAdd(&degf[d * 4 + 1], w * m1[e]);
    unsafeAtomicAdd(&degf[d * 4 + 2], w * m2[e]);
}

// ---------------- exclusive scan of counts (3 kernels) --------------------
__global__ void k_scan1(const int* __restrict__ cnt, int* __restrict__ off,
                        int* __restrict__ bsum, int n) {
    __shared__ int sh[256];
    int tid = threadIdx.x;
    int i0 = blockIdx.x * 1024 + tid * 4;
    int c[4]; int s = 0;
    #pragma unroll
    for (int q = 0; q < 4; q++) { int idx = i0 + q; c[q] = (idx < n) ? cnt[idx] : 0; s += c[q]; }
    sh[tid] = s; __syncthreads();
    for (int st = 1; st < 256; st <<= 1) {
        int v = (tid >= st) ? sh[tid - st] : 0;
        __syncthreads();
        sh[tid] += v;
        __syncthreads();
    }
    int incl = sh[tid];
    int ex = incl - s;
    if (tid == 255) bsum[blockIdx.x] = incl;
    int run = ex;
    #pragma unroll
    for (int q = 0; q < 4; q++) { int idx = i0 + q; if (idx <= n) off[idx] = run; run += c[q]; }
}

__global__ void k_scan2(const int* __restrict__ bsum, int* __restrict__ bex, int nb) {
    __shared__ int sh[256];
    int tid = threadIdx.x;
    int s = (tid < nb) ? bsum[tid] : 0;
    sh[tid] = s; __syncthreads();
    for (int st = 1; st < 256; st <<= 1) {
        int v = (tid >= st) ? sh[tid - st] : 0;
        __syncthreads();
        sh[tid] += v;
        __syncthreads();
    }
    if (tid < nb) bex[tid] = sh[tid] - s;
}

__global__ void k_scan3(int* __restrict__ off, int* __restrict__ cur,
                        const int* __restrict__ bex, int n) {
    int tid = threadIdx.x;
    int i0 = blockIdx.x * 1024 + tid * 4;
    int add = bex[blockIdx.x];
    #pragma unroll
    for (int q = 0; q < 4; q++) {
        int idx = i0 + q;
        if (idx <= n) {
            int v = off[idx] + add;
            off[idx] = v;
            if (idx < n) cur[idx] = v;
        }
    }
}

// ---------------- dinv_v = rsqrt(deg_v + 1) -------------------------------
__global__ void k_dinv(float* __restrict__ dv, int n) {
    int i = blockIdx.x * blockDim.x + threadIdx.x;
    if (i >= n) return;
    float4* p = (float4*)dv;
    float4 d = p[i];
    p[i] = make_float4(1.0f / sqrtf(d.x + 1.0f),
                       1.0f / sqrtf(d.y + 1.0f),
                       1.0f / sqrtf(d.z + 1.0f), 0.0f);
}

// ---------------- CSR fill: packed {norm0,norm1,norm2,src} per edge -------
__global__ void k_fill(const int* __restrict__ ei, const float* __restrict__ ew,
                       const float* __restrict__ m1, const float* __restrict__ m2,
                       const float4* __restrict__ dinv, int* __restrict__ cur,
                       float4* __restrict__ sorted, int E) {
    int e = blockIdx.x * blockDim.x + threadIdx.x;
    if (e >= E) return;
    int s = ei[e];
    int d = ei[E + e];
    float w = ew[e];
    float4 ds_ = dinv[s], dd = dinv[d];
    int pos = atomicAdd(&cur[d], 1);
    float w1v = w * m1[e], w2v = w * m2[e];
    sorted[pos] = make_float4(ds_.x * w * dd.x,
                              ds_.y * w1v * dd.y,
                              ds_.z * w2v * dd.z,
                              __int_as_float(s));
}

// ---------------- GEMM1: h1 = x (N x 512) @ Wc (512 x 96) ----------------
// BM=128, BK=32, 192 threads, 8x8 thread tile (16 row-groups x 12 col-groups)
__global__ __launch_bounds__(192) void k_gemm1(const float* __restrict__ x,
                                               const float* __restrict__ Wc,
                                               float* __restrict__ h1, int n) {
    __shared__ float xs[32][132];   // k-major, padded (132) to dodge store conflicts
    __shared__ float wsd[32][96];
    int tid = threadIdx.x;
    int m0 = blockIdx.x * 128;
    int rg = tid & 15, cg = tid >> 4;
    float acc[8][8] = {};
    for (int kt = 0; kt < F_DIMC; kt += 32) {
        // stage x tile (128 rows x 32 k), transposed into LDS
        for (int i = tid; i < 1024; i += 192) {
            int r = i >> 3, kc = i & 7;
            float4 v = make_float4(0.f, 0.f, 0.f, 0.f);
            int row = m0 + r;
            if (row < n) v = *(const float4*)&x[(size_t)row * F_DIMC + kt + kc * 4];
            xs[kc * 4 + 0][r] = v.x;
            xs[kc * 4 + 1][r] = v.y;
            xs[kc * 4 + 2][r] = v.z;
            xs[kc * 4 + 3][r] = v.w;
        }
        // stage Wc tile (32 k x 96 c)
        for (int i = tid; i < 768; i += 192) {
            int k = i / 24, c4 = i % 24;
            *(float4*)&wsd[k][c4 * 4] = *(const float4*)&Wc[(size_t)(kt + k) * 96 + c4 * 4];
        }
        __syncthreads();
        #pragma unroll 4
        for (int k = 0; k < 32; k++) {
            float a[8], b[8];
            *(float4*)&a[0] = *(float4*)&xs[k][rg * 8];
            *(float4*)&a[4] = *(float4*)&xs[k][rg * 8 + 4];
            *(float4*)&b[0] = *(float4*)&wsd[k][cg * 8];
            *(float4*)&b[4] = *(float4*)&wsd[k][cg * 8 + 4];
            #pragma unroll
            for (int i = 0; i < 8; i++) {
                #pragma unroll
                for (int j = 0; j < 8; j++) acc[i][j] += a[i] * b[j];
            }
        }
        __syncthreads();
    }
    #pragma unroll
    for (int i = 0; i < 8; i++) {
        int row = m0 + rg * 8 + i;
        if (row < n) {
            float4 v0 = make_float4(acc[i][0], acc[i][1], acc[i][2], acc[i][3]);
            float4 v1 = make_float4(acc[i][4], acc[i][5], acc[i][6], acc[i][7]);
            *(float4*)&h1[(size_t)row * 96 + cg * 8]     = v0;
            *(float4*)&h1[(size_t)row * 96 + cg * 8 + 4] = v1;
        }
    }
}

// ------- layer1 aggregation (+self loop, +b1, ReLU) fused with GEMM2 ------
// one block (96 threads) per node; thread t: view v=t>>5, channel j=t&31
__global__ __launch_bounds__(96) void k_agg1(const float* __restrict__ h1,
                                             const float4* __restrict__ sorted,
                                             const int* __restrict__ off,
                                             const float4* __restrict__ dinv,
                                             const float* __restrict__ b1,
                                             const float* __restrict__ W2,
                                             float* __restrict__ h2) {
    __shared__ float w2s[HIDC * HIDC];
    __shared__ float zrow[96];
    int t = threadIdx.x;
    for (int i = t; i < HIDC * HIDC; i += 96) w2s[i] = W2[i];
    int nidx = blockIdx.x;
    int v = t >> 5, j = t & 31;
    int p0 = off[nidx], p1 = off[nidx + 1];
    float acc = 0.f;
    int p = p0;
    for (; p + 1 < p1; p += 2) {
        float4 pk0 = sorted[p];
        float4 pk1 = sorted[p + 1];
        int s0 = __float_as_int(pk0.w);
        int s1 = __float_as_int(pk1.w);
        float n0 = (v == 0) ? pk0.x : ((v == 1) ? pk0.y : pk0.z);
        float n1 = (v == 0) ? pk1.x : ((v == 1) ? pk1.y : pk1.z);
        float g0 = h1[(size_t)s0 * 96 + t];
        float g1 = h1[(size_t)s1 * 96 + t];
        acc += g0 * n0;
        acc += g1 * n1;
    }
    if (p < p1) {
        float4 pk = sorted[p];
        int s = __float_as_int(pk.w);
        float nr = (v == 0) ? pk.x : ((v == 1) ? pk.y : pk.z);
        acc += h1[(size_t)s * 96 + t] * nr;
    }
    float4 dvq = dinv[nidx];
    float dvv = (v == 0) ? dvq.x : ((v == 1) ? dvq.y : dvq.z);
    float z = acc + h1[(size_t)nidx * 96 + t] * dvv * dvv + b1[j];
    z = fmaxf(z, 0.f);
    zrow[t] = z;
    __syncthreads();
    // fused GEMM2: h2[n][v*32+j] = sum_k z[n][v*32+k] * W2[k][j]
    float sum = 0.f;
    #pragma unroll
    for (int k = 0; k < HIDC; k++) sum += zrow[v * 32 + k] * w2s[k * 32 + j];
    h2[(size_t)nidx * 96 + t] = sum;
}

// ------- layer2 aggregation (+self loop, +b2, ReLU) → de-interleaved out --
__global__ __launch_bounds__(96) void k_agg2(const float* __restrict__ h2,
                                             const float4* __restrict__ sorted,
                                             const int* __restrict__ off,
                                             const float4* __restrict__ dinv,
                                             const float* __restrict__ b2,
                                             float* __restrict__ out, int nnodes) {
    int t = threadIdx.x;
    int nidx = blockIdx.x;
    int v = t >> 5, j = t & 31;
    int p0 = off[nidx], p1 = off[nidx + 1];
    float acc = 0.f;
    int p = p0;
    for (; p + 1 < p1; p += 2) {
        float4 pk0 = sorted[p];
        float4 pk1 = sorted[p + 1];
        int s0 = __float_as_int(pk0.w);
        int s1 = __float_as_int(pk1.w);
        float n0 = (v == 0) ? pk0.x : ((v == 1) ? pk0.y : pk0.z);
        float n1 = (v == 0) ? pk1.x : ((v == 1) ? pk1.y : pk1.z);
        float g0 = h2[(size_t)s0 * 96 + t];
        float g1 = h2[(size_t)s1 * 96 + t];
        acc += g0 * n0;
        acc += g1 * n1;
    }
    if (p < p1) {
        float4 pk = sorted[p];
        int s = __float_as_int(pk.w);
        float nr = (v == 0) ? pk.x : ((v == 1) ? pk.y : pk.z);
        acc += h2[(size_t)s * 96 + t] * nr;
    }
    float4 dvq = dinv[nidx];
    float dvv = (v == 0) ? dvq.x : ((v == 1) ? dvq.y : dvq.z);
    float z = acc + h2[(size_t)nidx * 96 + t] * dvv * dvv + b2[j];
    out[((size_t)v * nnodes + nidx) * HIDC + j] = fmaxf(z, 0.f);
}

extern "C" void kernel_launch(void* const* d_in, const int* in_sizes, int n_in,
                              void* d_out, int out_size, void* d_ws, size_t ws_size,
                              hipStream_t stream) {
    const float* x   = (const float*)d_in[0];
    const int*   ei  = (const int*)d_in[1];     // harness stages integers as int32
    const float* ew  = (const float*)d_in[2];
    const float* m1  = (const float*)d_in[3];
    const float* m2  = (const float*)d_in[4];
    const float* fm1 = (const float*)d_in[5];
    const float* fm2 = (const float*)d_in[6];
    const float* W1  = (const float*)d_in[7];
    const float* b1  = (const float*)d_in[8];
    const float* W2  = (const float*)d_in[9];
    const float* b2  = (const float*)d_in[10];
    float* out = (float*)d_out;
    int Nn = in_sizes[0] / F_DIMC;
    int Ee = in_sizes[2];
    (void)n_in; (void)out_size; (void)ws_size;

    char* ws = (char*)d_ws;
    size_t o = 0;
    auto carve = [&](size_t bytes) -> char* {
        char* p = ws + o;
        o = (o + bytes + 255) & ~(size_t)255;
        return p;
    };
    int*    cnt    = (int*)   carve((size_t)Nn * 4);          // counts, then cursor
    int*    off    = (int*)   carve(((size_t)Nn + 1) * 4);    // CSR offsets
    int*    bsum   = (int*)   carve(256 * 4);
    int*    bex    = (int*)   carve(256 * 4);
    float*  dinv   = (float*) carve((size_t)Nn * 16);         // degf -> dinv (float4/node)
    float4* sorted = (float4*)carve((size_t)Ee * 16);         // {n0,n1,n2,src} per edge
    float*  h1     = (float*) carve((size_t)Nn * 96 * 4);
    float*  h2     = (float*) carve((size_t)Nn * 96 * 4);
    float*  Wc     = (float*) carve((size_t)F_DIMC * 96 * 4);

    hipMemsetAsync(cnt, 0, (size_t)Nn * 4, stream);
    hipMemsetAsync(dinv, 0, (size_t)Nn * 16, stream);

    k_wc<<<(F_DIMC * HIDC + 255) / 256, 256, 0, stream>>>(W1, fm1, fm2, Wc);
    k_count<<<(Ee + 255) / 256, 256, 0, stream>>>(ei, ew, m1, m2, cnt, dinv, Ee);
    int nb = (Nn + 1023) / 1024;
    k_scan1<<<nb, 256, 0, stream>>>(cnt, off, bsum, Nn);
    k_scan2<<<1, 256, 0, stream>>>(bsum, bex, nb);
    k_scan3<<<nb, 256, 0, stream>>>(off, cnt, bex, Nn);
    k_dinv<<<(Nn + 255) / 256, 256, 0, stream>>>(dinv, Nn);
    k_fill<<<(Ee + 255) / 256, 256, 0, stream>>>(ei, ew, m1, m2, (const float4*)dinv,
                                                 cnt, sorted, Ee);
    k_gemm1<<<(Nn + 127) / 128, 192, 0, stream>>>(x, Wc, h1, Nn);
    k_agg1<<<Nn, 96, 0, stream>>>(h1, sorted, off, (const float4*)dinv, b1, W2, h2);
    k_agg2<<<Nn, 96, 0, stream>>>(h2, sorted, off, (const float4*)dinv, b2, out, Nn);
}

// Round 3
// 1401.437 us; speedup vs baseline: 1.2563x; 1.2563x over previous
//
#include <hip/hip_runtime.h>
#include <hip/hip_bf16.h>

#define F_DIMC 512
#define HIDC   32

// ---------------- Wc = [W1 | W1*fm1 | W1*fm2]  (512 x 96) ----------------
__global__ void k_wc(const float* __restrict__ W1, const float* __restrict__ fm1,
                     const float* __restrict__ fm2, float* __restrict__ Wc) {
    int i = blockIdx.x * blockDim.x + threadIdx.x;
    if (i >= F_DIMC * HIDC) return;
    int k = i / HIDC, j = i % HIDC;
    float w = W1[i];
    float* row = Wc + k * 96;
    row[j]      = w;
    row[32 + j] = w * fm1[k];
    row[64 + j] = w * fm2[k];
}

// ---------------- per-edge: degree counts (int atomic ONLY) ---------------
__global__ void k_count(const int* __restrict__ dst, int* __restrict__ cnt, int E) {
    int e = blockIdx.x * blockDim.x + threadIdx.x;
    if (e >= E) return;
    atomicAdd(&cnt[dst[e]], 1);
}

// ---------------- exclusive scan of counts (3 kernels) --------------------
__global__ void k_scan1(const int* __restrict__ cnt, int* __restrict__ off,
                        int* __restrict__ bsum, int n) {
    __shared__ int sh[256];
    int tid = threadIdx.x;
    int i0 = blockIdx.x * 1024 + tid * 4;
    int c[4]; int s = 0;
    #pragma unroll
    for (int q = 0; q < 4; q++) { int idx = i0 + q; c[q] = (idx < n) ? cnt[idx] : 0; s += c[q]; }
    sh[tid] = s; __syncthreads();
    for (int st = 1; st < 256; st <<= 1) {
        int v = (tid >= st) ? sh[tid - st] : 0;
        __syncthreads();
        sh[tid] += v;
        __syncthreads();
    }
    int incl = sh[tid];
    int ex = incl - s;
    if (tid == 255) bsum[blockIdx.x] = incl;
    int run = ex;
    #pragma unroll
    for (int q = 0; q < 4; q++) { int idx = i0 + q; if (idx <= n) off[idx] = run; run += c[q]; }
}

__global__ void k_scan2(const int* __restrict__ bsum, int* __restrict__ bex, int nb) {
    __shared__ int sh[256];
    int tid = threadIdx.x;
    int s = (tid < nb) ? bsum[tid] : 0;
    sh[tid] = s; __syncthreads();
    for (int st = 1; st < 256; st <<= 1) {
        int v = (tid >= st) ? sh[tid - st] : 0;
        __syncthreads();
        sh[tid] += v;
        __syncthreads();
    }
    if (tid < nb) bex[tid] = sh[tid] - s;
}

__global__ void k_scan3(int* __restrict__ off, int* __restrict__ cur,
                        const int* __restrict__ bex, int n) {
    int tid = threadIdx.x;
    int i0 = blockIdx.x * 1024 + tid * 4;
    int add = bex[blockIdx.x];
    #pragma unroll
    for (int q = 0; q < 4; q++) {
        int idx = i0 + q;
        if (idx <= n) {
            int v = off[idx] + add;
            off[idx] = v;
            if (idx < n) cur[idx] = v;
        }
    }
}

// ---------------- CSR fill: packed {w, w*m1, w*m2, src} per edge ----------
__global__ void k_fill(const int* __restrict__ ei, const float* __restrict__ ew,
                       const float* __restrict__ m1, const float* __restrict__ m2,
                       int* __restrict__ cur, float4* __restrict__ sorted, int E) {
    int e = blockIdx.x * blockDim.x + threadIdx.x;
    if (e >= E) return;
    int s = ei[e];
    int d = ei[E + e];
    float w = ew[e];
    int pos = atomicAdd(&cur[d], 1);
    sorted[pos] = make_float4(w, w * m1[e], w * m2[e], __int_as_float(s));
}

// ------- segmented sum over CSR rows -> dinv (4 lanes per node) -----------
__global__ __launch_bounds__(256) void k_deg(const float4* __restrict__ sorted,
                                             const int* __restrict__ off,
                                             float4* __restrict__ dinv, int n) {
    int t = blockIdx.x * 256 + threadIdx.x;
    int g = t >> 2;        // node
    int L = t & 3;         // lane within group
    if (g >= n) return;
    int p0 = off[g], p1 = off[g + 1];
    float sx = 0.f, sy = 0.f, sz = 0.f;
    for (int p = p0 + L; p < p1; p += 4) {
        float4 pk = sorted[p];
        sx += pk.x; sy += pk.y; sz += pk.z;
    }
    #pragma unroll
    for (int m = 1; m < 4; m <<= 1) {
        sx += __shfl_xor(sx, m);
        sy += __shfl_xor(sy, m);
        sz += __shfl_xor(sz, m);
    }
    if (L == 0)
        dinv[g] = make_float4(1.0f / sqrtf(sx + 1.0f),
                              1.0f / sqrtf(sy + 1.0f),
                              1.0f / sqrtf(sz + 1.0f), 0.0f);
}

__device__ __forceinline__ float sel3(float4 q, int v) {
    return (v == 0) ? q.x : ((v == 1) ? q.y : q.z);
}

// ------- layer1 aggregation (+self loop, +b1, ReLU) fused with GEMM2 ------
// one block (96 threads) per node; thread t: view v=t>>5, channel j=t&31
__global__ __launch_bounds__(96) void k_agg1(const float* __restrict__ h1,
                                             const float4* __restrict__ sorted,
                                             const int* __restrict__ off,
                                             const float4* __restrict__ dinv,
                                             const float* __restrict__ b1,
                                             const float* __restrict__ W2,
                                             float* __restrict__ h2) {
    __shared__ float w2s[HIDC * HIDC];
    __shared__ float zrow[96];
    int t = threadIdx.x;
    for (int i = t; i < HIDC * HIDC; i += 96) w2s[i] = W2[i];
    int nidx = blockIdx.x;
    int v = t >> 5, j = t & 31;
    int p0 = off[nidx], p1 = off[nidx + 1];
    float acc = 0.f;
    int p = p0;
    for (; p + 3 < p1; p += 4) {
        float4 pk0 = sorted[p],     pk1 = sorted[p + 1];
        float4 pk2 = sorted[p + 2], pk3 = sorted[p + 3];
        int s0 = __float_as_int(pk0.w), s1 = __float_as_int(pk1.w);
        int s2 = __float_as_int(pk2.w), s3 = __float_as_int(pk3.w);
        float n0 = sel3(pk0, v) * sel3(dinv[s0], v);
        float n1 = sel3(pk1, v) * sel3(dinv[s1], v);
        float n2 = sel3(pk2, v) * sel3(dinv[s2], v);
        float n3 = sel3(pk3, v) * sel3(dinv[s3], v);
        float g0 = h1[(size_t)s0 * 96 + t];
        float g1 = h1[(size_t)s1 * 96 + t];
        float g2 = h1[(size_t)s2 * 96 + t];
        float g3 = h1[(size_t)s3 * 96 + t];
        acc += g0 * n0 + g1 * n1 + g2 * n2 + g3 * n3;
    }
    for (; p < p1; p++) {
        float4 pk = sorted[p];
        int s = __float_as_int(pk.w);
        acc += h1[(size_t)s * 96 + t] * sel3(pk, v) * sel3(dinv[s], v);
    }
    float dvv = sel3(dinv[nidx], v);
    float z = (acc + h1[(size_t)nidx * 96 + t] * dvv) * dvv + b1[j];
    z = fmaxf(z, 0.f);
    zrow[t] = z;
    __syncthreads();
    // fused GEMM2: h2[n][v*32+j] = sum_k z[n][v*32+k] * W2[k][j]
    float sum = 0.f;
    #pragma unroll
    for (int k = 0; k < HIDC; k++) sum += zrow[v * 32 + k] * w2s[k * 32 + j];
    h2[(size_t)nidx * 96 + t] = sum;
}

// ------- layer2 aggregation (+self loop, +b2, ReLU) → de-interleaved out --
__global__ __launch_bounds__(96) void k_agg2(const float* __restrict__ h2,
                                             const float4* __restrict__ sorted,
                                             const int* __restrict__ off,
                                             const float4* __restrict__ dinv,
                                             const float* __restrict__ b2,
                                             float* __restrict__ out, int nnodes) {
    int t = threadIdx.x;
    int nidx = blockIdx.x;
    int v = t >> 5, j = t & 31;
    int p0 = off[nidx], p1 = off[nidx + 1];
    float acc = 0.f;
    int p = p0;
    for (; p + 3 < p1; p += 4) {
        float4 pk0 = sorted[p],     pk1 = sorted[p + 1];
        float4 pk2 = sorted[p + 2], pk3 = sorted[p + 3];
        int s0 = __float_as_int(pk0.w), s1 = __float_as_int(pk1.w);
        int s2 = __float_as_int(pk2.w), s3 = __float_as_int(pk3.w);
        float n0 = sel3(pk0, v) * sel3(dinv[s0], v);
        float n1 = sel3(pk1, v) * sel3(dinv[s1], v);
        float n2 = sel3(pk2, v) * sel3(dinv[s2], v);
        float n3 = sel3(pk3, v) * sel3(dinv[s3], v);
        float g0 = h2[(size_t)s0 * 96 + t];
        float g1 = h2[(size_t)s1 * 96 + t];
        float g2 = h2[(size_t)s2 * 96 + t];
        float g3 = h2[(size_t)s3 * 96 + t];
        acc += g0 * n0 + g1 * n1 + g2 * n2 + g3 * n3;
    }
    for (; p < p1; p++) {
        float4 pk = sorted[p];
        int s = __float_as_int(pk.w);
        acc += h2[(size_t)s * 96 + t] * sel3(pk, v) * sel3(dinv[s], v);
    }
    float dvv = sel3(dinv[nidx], v);
    float z = (acc + h2[(size_t)nidx * 96 + t] * dvv) * dvv + b2[j];
    out[((size_t)v * nnodes + nidx) * HIDC + j] = fmaxf(z, 0.f);
}

// ---------------- GEMM1: h1 = x (N x 512) @ Wc (512 x 96) ----------------
// BM=128, BK=32, 192 threads, 8x8 thread tile (16 row-groups x 12 col-groups)
__global__ __launch_bounds__(192) void k_gemm1(const float* __restrict__ x,
                                               const float* __restrict__ Wc,
                                               float* __restrict__ h1, int n) {
    __shared__ float xs[32][132];   // k-major, padded to dodge store conflicts
    __shared__ float wsd[32][96];
    int tid = threadIdx.x;
    int m0 = blockIdx.x * 128;
    int rg = tid & 15, cg = tid >> 4;
    float acc[8][8] = {};
    for (int kt = 0; kt < F_DIMC; kt += 32) {
        for (int i = tid; i < 1024; i += 192) {
            int r = i >> 3, kc = i & 7;
            float4 v = make_float4(0.f, 0.f, 0.f, 0.f);
            int row = m0 + r;
            if (row < n) v = *(const float4*)&x[(size_t)row * F_DIMC + kt + kc * 4];
            xs[kc * 4 + 0][r] = v.x;
            xs[kc * 4 + 1][r] = v.y;
            xs[kc * 4 + 2][r] = v.z;
            xs[kc * 4 + 3][r] = v.w;
        }
        for (int i = tid; i < 768; i += 192) {
            int k = i / 24, c4 = i % 24;
            *(float4*)&wsd[k][c4 * 4] = *(const float4*)&Wc[(size_t)(kt + k) * 96 + c4 * 4];
        }
        __syncthreads();
        #pragma unroll 4
        for (int k = 0; k < 32; k++) {
            float a[8], b[8];
            *(float4*)&a[0] = *(float4*)&xs[k][rg * 8];
            *(float4*)&a[4] = *(float4*)&xs[k][rg * 8 + 4];
            *(float4*)&b[0] = *(float4*)&wsd[k][cg * 8];
            *(float4*)&b[4] = *(float4*)&wsd[k][cg * 8 + 4];
            #pragma unroll
            for (int i = 0; i < 8; i++) {
                #pragma unroll
                for (int j = 0; j < 8; j++) acc[i][j] += a[i] * b[j];
            }
        }
        __syncthreads();
    }
    #pragma unroll
    for (int i = 0; i < 8; i++) {
        int row = m0 + rg * 8 + i;
        if (row < n) {
            float4 v0 = make_float4(acc[i][0], acc[i][1], acc[i][2], acc[i][3]);
            float4 v1 = make_float4(acc[i][4], acc[i][5], acc[i][6], acc[i][7]);
            *(float4*)&h1[(size_t)row * 96 + cg * 8]     = v0;
            *(float4*)&h1[(size_t)row * 96 + cg * 8 + 4] = v1;
        }
    }
}

extern "C" void kernel_launch(void* const* d_in, const int* in_sizes, int n_in,
                              void* d_out, int out_size, void* d_ws, size_t ws_size,
                              hipStream_t stream) {
    const float* x   = (const float*)d_in[0];
    const int*   ei  = (const int*)d_in[1];     // harness stages integers as int32
    const float* ew  = (const float*)d_in[2];
    const float* m1  = (const float*)d_in[3];
    const float* m2  = (const float*)d_in[4];
    const float* fm1 = (const float*)d_in[5];
    const float* fm2 = (const float*)d_in[6];
    const float* W1  = (const float*)d_in[7];
    const float* b1  = (const float*)d_in[8];
    const float* W2  = (const float*)d_in[9];
    const float* b2  = (const float*)d_in[10];
    float* out = (float*)d_out;
    int Nn = in_sizes[0] / F_DIMC;
    int Ee = in_sizes[2];
    (void)n_in; (void)out_size; (void)ws_size;

    char* ws = (char*)d_ws;
    size_t o = 0;
    auto carve = [&](size_t bytes) -> char* {
        char* p = ws + o;
        o = (o + bytes + 255) & ~(size_t)255;
        return p;
    };
    int*    cnt    = (int*)   carve((size_t)Nn * 4);          // counts, then cursor
    int*    off    = (int*)   carve(((size_t)Nn + 1) * 4);    // CSR offsets
    int*    bsum   = (int*)   carve(256 * 4);
    int*    bex    = (int*)   carve(256 * 4);
    float4* dinv   = (float4*)carve((size_t)Nn * 16);         // rsqrt(deg+1), 3 views
    float4* sorted = (float4*)carve((size_t)Ee * 16);         // {w0,w1,w2,src} per edge
    float*  h1     = (float*) carve((size_t)Nn * 96 * 4);
    float*  h2     = (float*) carve((size_t)Nn * 96 * 4);
    float*  Wc     = (float*) carve((size_t)F_DIMC * 96 * 4);

    hipMemsetAsync(cnt, 0, (size_t)Nn * 4, stream);

    k_wc<<<(F_DIMC * HIDC + 255) / 256, 256, 0, stream>>>(W1, fm1, fm2, Wc);
    k_count<<<(Ee + 255) / 256, 256, 0, stream>>>(ei + Ee, cnt, Ee);
    int nb = (Nn + 1023) / 1024;
    k_scan1<<<nb, 256, 0, stream>>>(cnt, off, bsum, Nn);
    k_scan2<<<1, 256, 0, stream>>>(bsum, bex, nb);
    k_scan3<<<nb, 256, 0, stream>>>(off, cnt, bex, Nn);
    k_fill<<<(Ee + 255) / 256, 256, 0, stream>>>(ei, ew, m1, m2, cnt, sorted, Ee);
    k_deg<<<(Nn * 4 + 255) / 256, 256, 0, stream>>>(sorted, off, dinv, Nn);
    k_gemm1<<<(Nn + 127) / 128, 192, 0, stream>>>(x, Wc, h1, Nn);
    k_agg1<<<Nn, 96, 0, stream>>>(h1, sorted, off, dinv, b1, W2, h2);
    k_agg2<<<Nn, 96, 0, stream>>>(h2, sorted, off, dinv, b2, out, Nn);
}

// Round 4
// 1229.388 us; speedup vs baseline: 1.4321x; 1.1399x over previous
//
#include <hip/hip_runtime.h>
#include <hip/hip_bf16.h>

#define F_DIMC 512
#define HIDC   32
#define NPB    4     // nodes per aggregation block

// ---------------- Wc = [W1 | W1*fm1 | W1*fm2]  (512 x 96) ----------------
__global__ void k_wc(const float* __restrict__ W1, const float* __restrict__ fm1,
                     const float* __restrict__ fm2, float* __restrict__ Wc) {
    int i = blockIdx.x * blockDim.x + threadIdx.x;
    if (i >= F_DIMC * HIDC) return;
    int k = i / HIDC, j = i % HIDC;
    float w = W1[i];
    float* row = Wc + k * 96;
    row[j]      = w;
    row[32 + j] = w * fm1[k];
    row[64 + j] = w * fm2[k];
}

// ---------------- per-edge: degree counts (int atomic ONLY) ---------------
__global__ void k_count(const int* __restrict__ dst, int* __restrict__ cnt, int E) {
    int e = blockIdx.x * blockDim.x + threadIdx.x;
    if (e >= E) return;
    atomicAdd(&cnt[dst[e]], 1);
}

// ---------------- exclusive scan of counts (3 kernels) --------------------
__global__ void k_scan1(const int* __restrict__ cnt, int* __restrict__ off,
                        int* __restrict__ bsum, int n) {
    __shared__ int sh[256];
    int tid = threadIdx.x;
    int i0 = blockIdx.x * 1024 + tid * 4;
    int c[4]; int s = 0;
    #pragma unroll
    for (int q = 0; q < 4; q++) { int idx = i0 + q; c[q] = (idx < n) ? cnt[idx] : 0; s += c[q]; }
    sh[tid] = s; __syncthreads();
    for (int st = 1; st < 256; st <<= 1) {
        int v = (tid >= st) ? sh[tid - st] : 0;
        __syncthreads();
        sh[tid] += v;
        __syncthreads();
    }
    int incl = sh[tid];
    int ex = incl - s;
    if (tid == 255) bsum[blockIdx.x] = incl;
    int run = ex;
    #pragma unroll
    for (int q = 0; q < 4; q++) { int idx = i0 + q; if (idx <= n) off[idx] = run; run += c[q]; }
}

__global__ void k_scan2(const int* __restrict__ bsum, int* __restrict__ bex, int nb) {
    __shared__ int sh[256];
    int tid = threadIdx.x;
    int s = (tid < nb) ? bsum[tid] : 0;
    sh[tid] = s; __syncthreads();
    for (int st = 1; st < 256; st <<= 1) {
        int v = (tid >= st) ? sh[tid - st] : 0;
        __syncthreads();
        sh[tid] += v;
        __syncthreads();
    }
    if (tid < nb) bex[tid] = sh[tid] - s;
}

__global__ void k_scan3(int* __restrict__ off, int* __restrict__ cur,
                        const int* __restrict__ bex, int n) {
    int tid = threadIdx.x;
    int i0 = blockIdx.x * 1024 + tid * 4;
    int add = bex[blockIdx.x];
    #pragma unroll
    for (int q = 0; q < 4; q++) {
        int idx = i0 + q;
        if (idx <= n) {
            int v = off[idx] + add;
            off[idx] = v;
            if (idx < n) cur[idx] = v;
        }
    }
}

// ---------------- CSR fill: packed {w, w*m1, w*m2, src} per edge ----------
__global__ void k_fill(const int* __restrict__ ei, const float* __restrict__ ew,
                       const float* __restrict__ m1, const float* __restrict__ m2,
                       int* __restrict__ cur, float4* __restrict__ sorted, int E) {
    int e = blockIdx.x * blockDim.x + threadIdx.x;
    if (e >= E) return;
    int s = ei[e];
    int d = ei[E + e];
    float w = ew[e];
    int pos = atomicAdd(&cur[d], 1);
    sorted[pos] = make_float4(w, w * m1[e], w * m2[e], __int_as_float(s));
}

// ------- segmented sum over CSR rows -> dinv (4 lanes per node) -----------
__global__ __launch_bounds__(256) void k_deg(const float4* __restrict__ sorted,
                                             const int* __restrict__ off,
                                             float4* __restrict__ dinv, int n) {
    int t = blockIdx.x * 256 + threadIdx.x;
    int g = t >> 2;        // node
    int L = t & 3;         // lane within group
    if (g >= n) return;
    int p0 = off[g], p1 = off[g + 1];
    float sx = 0.f, sy = 0.f, sz = 0.f;
    for (int p = p0 + L; p < p1; p += 4) {
        float4 pk = sorted[p];
        sx += pk.x; sy += pk.y; sz += pk.z;
    }
    #pragma unroll
    for (int m = 1; m < 4; m <<= 1) {
        sx += __shfl_xor(sx, m);
        sy += __shfl_xor(sy, m);
        sz += __shfl_xor(sz, m);
    }
    if (L == 0)
        dinv[g] = make_float4(1.0f / sqrtf(sx + 1.0f),
                              1.0f / sqrtf(sy + 1.0f),
                              1.0f / sqrtf(sz + 1.0f), 0.0f);
}

__device__ __forceinline__ float sel3(float4 q, int v) {
    return (v == 0) ? q.x : ((v == 1) ? q.y : q.z);
}

// ------- layer1 aggregation (+self loop, +b1, ReLU) fused with GEMM2 ------
// block = 384 threads = NPB nodes x (4 edge-groups x 24 float4-lanes)
__global__ __launch_bounds__(384) void k_agg1(const float* __restrict__ h1,
                                              const float4* __restrict__ sorted,
                                              const int* __restrict__ off,
                                              const float* __restrict__ dinvf,
                                              const float* __restrict__ b1,
                                              const float* __restrict__ W2,
                                              float* __restrict__ h2, int n) {
    __shared__ float  w2s[HIDC * HIDC];
    __shared__ float4 red[NPB][4][24];
    __shared__ float  zrow[NPB][96];
    int t = threadIdx.x;
    for (int i = t; i < HIDC * HIDC; i += 384) w2s[i] = W2[i];
    int nl = t / 96, tn = t % 96;
    int nidx = blockIdx.x * NPB + nl;
    int eg = tn / 24, c4 = tn % 24;
    int ch0 = c4 * 4;
    int v = ch0 >> 5;
    bool valid = nidx < n;
    float4 acc = make_float4(0.f, 0.f, 0.f, 0.f);
    if (valid) {
        int p0 = off[nidx], p1 = off[nidx + 1];
        int p = p0 + eg;
        for (; p + 4 < p1; p += 8) {
            float4 pk0 = sorted[p];
            float4 pk1 = sorted[p + 4];
            int s0 = __float_as_int(pk0.w);
            int s1 = __float_as_int(pk1.w);
            float nw0 = sel3(pk0, v) * dinvf[s0 * 4 + v];
            float nw1 = sel3(pk1, v) * dinvf[s1 * 4 + v];
            float4 g0 = *(const float4*)&h1[(size_t)s0 * 96 + ch0];
            float4 g1 = *(const float4*)&h1[(size_t)s1 * 96 + ch0];
            acc.x += g0.x * nw0 + g1.x * nw1;
            acc.y += g0.y * nw0 + g1.y * nw1;
            acc.z += g0.z * nw0 + g1.z * nw1;
            acc.w += g0.w * nw0 + g1.w * nw1;
        }
        if (p < p1) {
            float4 pk = sorted[p];
            int s = __float_as_int(pk.w);
            float nw = sel3(pk, v) * dinvf[s * 4 + v];
            float4 g = *(const float4*)&h1[(size_t)s * 96 + ch0];
            acc.x += g.x * nw; acc.y += g.y * nw;
            acc.z += g.z * nw; acc.w += g.w * nw;
        }
    }
    red[nl][eg][c4] = acc;
    __syncthreads();
    if (eg == 0 && valid) {
        float4 r0 = red[nl][0][c4], r1 = red[nl][1][c4];
        float4 r2 = red[nl][2][c4], r3 = red[nl][3][c4];
        float dvv = dinvf[nidx * 4 + v];
        float4 hs = *(const float4*)&h1[(size_t)nidx * 96 + ch0];
        float4 bb = *(const float4*)&b1[ch0 & 31];
        float4 z;
        z.x = fmaxf((r0.x + r1.x + r2.x + r3.x + hs.x * dvv) * dvv + bb.x, 0.f);
        z.y = fmaxf((r0.y + r1.y + r2.y + r3.y + hs.y * dvv) * dvv + bb.y, 0.f);
        z.z = fmaxf((r0.z + r1.z + r2.z + r3.z + hs.z * dvv) * dvv + bb.z, 0.f);
        z.w = fmaxf((r0.w + r1.w + r2.w + r3.w + hs.w * dvv) * dvv + bb.w, 0.f);
        *(float4*)&zrow[nl][ch0] = z;
    }
    __syncthreads();
    if (valid) {
        int j = tn & 31, v2 = tn >> 5;
        float sum = 0.f;
        #pragma unroll
        for (int k = 0; k < HIDC; k++) sum += zrow[nl][v2 * 32 + k] * w2s[k * 32 + j];
        h2[(size_t)nidx * 96 + tn] = sum;
    }
}

// ------- layer2 aggregation (+self loop, +b2, ReLU) → de-interleaved out --
__global__ __launch_bounds__(384) void k_agg2(const float* __restrict__ h2,
                                              const float4* __restrict__ sorted,
                                              const int* __restrict__ off,
                                              const float* __restrict__ dinvf,
                                              const float* __restrict__ b2,
                                              float* __restrict__ out, int n) {
    __shared__ float4 red[NPB][4][24];
    int t = threadIdx.x;
    int nl = t / 96, tn = t % 96;
    int nidx = blockIdx.x * NPB + nl;
    int eg = tn / 24, c4 = tn % 24;
    int ch0 = c4 * 4;
    int v = ch0 >> 5;
    bool valid = nidx < n;
    float4 acc = make_float4(0.f, 0.f, 0.f, 0.f);
    if (valid) {
        int p0 = off[nidx], p1 = off[nidx + 1];
        int p = p0 + eg;
        for (; p + 4 < p1; p += 8) {
            float4 pk0 = sorted[p];
            float4 pk1 = sorted[p + 4];
            int s0 = __float_as_int(pk0.w);
            int s1 = __float_as_int(pk1.w);
            float nw0 = sel3(pk0, v) * dinvf[s0 * 4 + v];
            float nw1 = sel3(pk1, v) * dinvf[s1 * 4 + v];
            float4 g0 = *(const float4*)&h2[(size_t)s0 * 96 + ch0];
            float4 g1 = *(const float4*)&h2[(size_t)s1 * 96 + ch0];
            acc.x += g0.x * nw0 + g1.x * nw1;
            acc.y += g0.y * nw0 + g1.y * nw1;
            acc.z += g0.z * nw0 + g1.z * nw1;
            acc.w += g0.w * nw0 + g1.w * nw1;
        }
        if (p < p1) {
            float4 pk = sorted[p];
            int s = __float_as_int(pk.w);
            float nw = sel3(pk, v) * dinvf[s * 4 + v];
            float4 g = *(const float4*)&h2[(size_t)s * 96 + ch0];
            acc.x += g.x * nw; acc.y += g.y * nw;
            acc.z += g.z * nw; acc.w += g.w * nw;
        }
    }
    red[nl][eg][c4] = acc;
    __syncthreads();
    if (eg == 0 && valid) {
        float4 r0 = red[nl][0][c4], r1 = red[nl][1][c4];
        float4 r2 = red[nl][2][c4], r3 = red[nl][3][c4];
        float dvv = dinvf[nidx * 4 + v];
        float4 hs = *(const float4*)&h2[(size_t)nidx * 96 + ch0];
        float4 bb = *(const float4*)&b2[ch0 & 31];
        float4 z;
        z.x = fmaxf((r0.x + r1.x + r2.x + r3.x + hs.x * dvv) * dvv + bb.x, 0.f);
        z.y = fmaxf((r0.y + r1.y + r2.y + r3.y + hs.y * dvv) * dvv + bb.y, 0.f);
        z.z = fmaxf((r0.z + r1.z + r2.z + r3.z + hs.z * dvv) * dvv + bb.z, 0.f);
        z.w = fmaxf((r0.w + r1.w + r2.w + r3.w + hs.w * dvv) * dvv + bb.w, 0.f);
        *(float4*)&out[((size_t)v * n + nidx) * HIDC + (ch0 & 31)] = z;
    }
}

// ---------------- GEMM1: h1 = x (N x 512) @ Wc (512 x 96) ----------------
// BM=128, BK=32, 192 threads, 8x8 thread tile (16 row-groups x 12 col-groups)
__global__ __launch_bounds__(192) void k_gemm1(const float* __restrict__ x,
                                               const float* __restrict__ Wc,
                                               float* __restrict__ h1, int n) {
    __shared__ float xs[32][132];   // k-major, padded to dodge store conflicts
    __shared__ float wsd[32][96];
    int tid = threadIdx.x;
    int m0 = blockIdx.x * 128;
    int rg = tid & 15, cg = tid >> 4;
    float acc[8][8] = {};
    for (int kt = 0; kt < F_DIMC; kt += 32) {
        for (int i = tid; i < 1024; i += 192) {
            int r = i >> 3, kc = i & 7;
            float4 v = make_float4(0.f, 0.f, 0.f, 0.f);
            int row = m0 + r;
            if (row < n) v = *(const float4*)&x[(size_t)row * F_DIMC + kt + kc * 4];
            xs[kc * 4 + 0][r] = v.x;
            xs[kc * 4 + 1][r] = v.y;
            xs[kc * 4 + 2][r] = v.z;
            xs[kc * 4 + 3][r] = v.w;
        }
        for (int i = tid; i < 768; i += 192) {
            int k = i / 24, c4 = i % 24;
            *(float4*)&wsd[k][c4 * 4] = *(const float4*)&Wc[(size_t)(kt + k) * 96 + c4 * 4];
        }
        __syncthreads();
        #pragma unroll 4
        for (int k = 0; k < 32; k++) {
            float a[8], b[8];
            *(float4*)&a[0] = *(float4*)&xs[k][rg * 8];
            *(float4*)&a[4] = *(float4*)&xs[k][rg * 8 + 4];
            *(float4*)&b[0] = *(float4*)&wsd[k][cg * 8];
            *(float4*)&b[4] = *(float4*)&wsd[k][cg * 8 + 4];
            #pragma unroll
            for (int i = 0; i < 8; i++) {
                #pragma unroll
                for (int j = 0; j < 8; j++) acc[i][j] += a[i] * b[j];
            }
        }
        __syncthreads();
    }
    #pragma unroll
    for (int i = 0; i < 8; i++) {
        int row = m0 + rg * 8 + i;
        if (row < n) {
            float4 v0 = make_float4(acc[i][0], acc[i][1], acc[i][2], acc[i][3]);
            float4 v1 = make_float4(acc[i][4], acc[i][5], acc[i][6], acc[i][7]);
            *(float4*)&h1[(size_t)row * 96 + cg * 8]     = v0;
            *(float4*)&h1[(size_t)row * 96 + cg * 8 + 4] = v1;
        }
    }
}

extern "C" void kernel_launch(void* const* d_in, const int* in_sizes, int n_in,
                              void* d_out, int out_size, void* d_ws, size_t ws_size,
                              hipStream_t stream) {
    const float* x   = (const float*)d_in[0];
    const int*   ei  = (const int*)d_in[1];     // harness stages integers as int32
    const float* ew  = (const float*)d_in[2];
    const float* m1  = (const float*)d_in[3];
    const float* m2  = (const float*)d_in[4];
    const float* fm1 = (const float*)d_in[5];
    const float* fm2 = (const float*)d_in[6];
    const float* W1  = (const float*)d_in[7];
    const float* b1  = (const float*)d_in[8];
    const float* W2  = (const float*)d_in[9];
    const float* b2  = (const float*)d_in[10];
    float* out = (float*)d_out;
    int Nn = in_sizes[0] / F_DIMC;
    int Ee = in_sizes[2];
    (void)n_in; (void)out_size; (void)ws_size;

    char* ws = (char*)d_ws;
    size_t o = 0;
    auto carve = [&](size_t bytes) -> char* {
        char* p = ws + o;
        o = (o + bytes + 255) & ~(size_t)255;
        return p;
    };
    int*    cnt    = (int*)   carve((size_t)Nn * 4);          // counts, then cursor
    int*    off    = (int*)   carve(((size_t)Nn + 1) * 4);    // CSR offsets
    int*    bsum   = (int*)   carve(256 * 4);
    int*    bex    = (int*)   carve(256 * 4);
    float4* dinv   = (float4*)carve((size_t)Nn * 16);         // rsqrt(deg+1), 3 views
    float4* sorted = (float4*)carve((size_t)Ee * 16);         // {w0,w1,w2,src} per edge
    float*  h1     = (float*) carve((size_t)Nn * 96 * 4);
    float*  h2     = (float*) carve((size_t)Nn * 96 * 4);
    float*  Wc     = (float*) carve((size_t)F_DIMC * 96 * 4);

    hipMemsetAsync(cnt, 0, (size_t)Nn * 4, stream);

    k_wc<<<(F_DIMC * HIDC + 255) / 256, 256, 0, stream>>>(W1, fm1, fm2, Wc);
    k_count<<<(Ee + 255) / 256, 256, 0, stream>>>(ei + Ee, cnt, Ee);
    int nb = (Nn + 1023) / 1024;
    k_scan1<<<nb, 256, 0, stream>>>(cnt, off, bsum, Nn);
    k_scan2<<<1, 256, 0, stream>>>(bsum, bex, nb);
    k_scan3<<<nb, 256, 0, stream>>>(off, cnt, bex, Nn);
    k_fill<<<(Ee + 255) / 256, 256, 0, stream>>>(ei, ew, m1, m2, cnt, sorted, Ee);
    k_deg<<<(Nn * 4 + 255) / 256, 256, 0, stream>>>(sorted, off, dinv, Nn);
    k_gemm1<<<(Nn + 127) / 128, 192, 0, stream>>>(x, Wc, h1, Nn);
    k_agg1<<<(Nn + NPB - 1) / NPB, 384, 0, stream>>>(h1, sorted, off, (const float*)dinv,
                                                     b1, W2, h2, Nn);
    k_agg2<<<(Nn + NPB - 1) / NPB, 384, 0, stream>>>(h2, sorted, off, (const float*)dinv,
                                                     b2, out, Nn);
}

// Round 6
// 1063.957 us; speedup vs baseline: 1.6548x; 1.1555x over previous
//
#include <hip/hip_runtime.h>
#include <hip/hip_bf16.h>

#define F_DIMC 512
#define HIDC   32
#define NPB    4     // nodes per aggregation block

// ---------------- Wc = [W1 | W1*fm1 | W1*fm2]  (512 x 96) ----------------
__global__ void k_wc(const float* __restrict__ W1, const float* __restrict__ fm1,
                     const float* __restrict__ fm2, float* __restrict__ Wc) {
    int i = blockIdx.x * blockDim.x + threadIdx.x;
    if (i >= F_DIMC * HIDC) return;
    int k = i / HIDC, j = i % HIDC;
    float w = W1[i];
    float* row = Wc + k * 96;
    row[j]      = w;
    row[32 + j] = w * fm1[k];
    row[64 + j] = w * fm2[k];
}

// ------ per-edge: degree counts; atomic return value = rank within dst ----
__global__ void k_count(const int* __restrict__ dst, int* __restrict__ cnt,
                        int* __restrict__ rank, int E) {
    int e = blockIdx.x * blockDim.x + threadIdx.x;
    if (e >= E) return;
    rank[e] = atomicAdd(&cnt[dst[e]], 1);
}

// ---------------- exclusive scan of counts (3 kernels) --------------------
__global__ void k_scan1(const int* __restrict__ cnt, int* __restrict__ off,
                        int* __restrict__ bsum, int n) {
    __shared__ int sh[256];
    int tid = threadIdx.x;
    int i0 = blockIdx.x * 1024 + tid * 4;
    int c[4]; int s = 0;
    #pragma unroll
    for (int q = 0; q < 4; q++) { int idx = i0 + q; c[q] = (idx < n) ? cnt[idx] : 0; s += c[q]; }
    sh[tid] = s; __syncthreads();
    for (int st = 1; st < 256; st <<= 1) {
        int v = (tid >= st) ? sh[tid - st] : 0;
        __syncthreads();
        sh[tid] += v;
        __syncthreads();
    }
    int incl = sh[tid];
    int ex = incl - s;
    if (tid == 255) bsum[blockIdx.x] = incl;
    int run = ex;
    #pragma unroll
    for (int q = 0; q < 4; q++) { int idx = i0 + q; if (idx <= n) off[idx] = run; run += c[q]; }
}

__global__ void k_scan2(const int* __restrict__ bsum, int* __restrict__ bex, int nb) {
    __shared__ int sh[256];
    int tid = threadIdx.x;
    int s = (tid < nb) ? bsum[tid] : 0;
    sh[tid] = s; __syncthreads();
    for (int st = 1; st < 256; st <<= 1) {
        int v = (tid >= st) ? sh[tid - st] : 0;
        __syncthreads();
        sh[tid] += v;
        __syncthreads();
    }
    if (tid < nb) bex[tid] = sh[tid] - s;
}

__global__ void k_scan3(int* __restrict__ off, const int* __restrict__ bex, int n) {
    int tid = threadIdx.x;
    int i0 = blockIdx.x * 1024 + tid * 4;
    int add = bex[blockIdx.x];
    #pragma unroll
    for (int q = 0; q < 4; q++) {
        int idx = i0 + q;
        if (idx <= n) off[idx] += add;
    }
}

// ------- CSR fill (NO atomics): pos = off[dst] + rank; 8B payload ---------
// payload = {w, bits} with bits = src | m1bit<<30 | m2bit<<31 (masks are 0/1)
__global__ void k_fill(const int* __restrict__ ei, const float* __restrict__ ew,
                       const float* __restrict__ m1, const float* __restrict__ m2,
                       const int* __restrict__ off, const int* __restrict__ rank,
                       float2* __restrict__ sorted, int E) {
    int e = blockIdx.x * blockDim.x + threadIdx.x;
    if (e >= E) return;
    int s = ei[e];
    int d = ei[E + e];
    unsigned bits = (unsigned)s;
    if (m1[e] > 0.5f) bits |= (1u << 30);
    if (m2[e] > 0.5f) bits |= (1u << 31);
    int pos = off[d] + rank[e];
    sorted[pos] = make_float2(ew[e], __uint_as_float(bits));
}

// ------- segmented sum over CSR rows -> dinv (4 lanes per node) -----------
__global__ __launch_bounds__(256) void k_deg(const float2* __restrict__ sorted,
                                             const int* __restrict__ off,
                                             float4* __restrict__ dinv, int n) {
    int t = blockIdx.x * 256 + threadIdx.x;
    int g = t >> 2;        // node
    int L = t & 3;         // lane within group
    if (g >= n) return;
    int p0 = off[g], p1 = off[g + 1];
    float sx = 0.f, sy = 0.f, sz = 0.f;
    for (int p = p0 + L; p < p1; p += 4) {
        float2 pk = sorted[p];
        unsigned bb = __float_as_uint(pk.y);
        sx += pk.x;
        sy += (bb & (1u << 30)) ? pk.x : 0.f;
        sz += (bb & (1u << 31)) ? pk.x : 0.f;
    }
    #pragma unroll
    for (int m = 1; m < 4; m <<= 1) {
        sx += __shfl_xor(sx, m);
        sy += __shfl_xor(sy, m);
        sz += __shfl_xor(sz, m);
    }
    if (L == 0)
        dinv[g] = make_float4(1.0f / sqrtf(sx + 1.0f),
                              1.0f / sqrtf(sy + 1.0f),
                              1.0f / sqrtf(sz + 1.0f), 0.0f);
}

// ------- layer1 aggregation (+self loop, +b1, ReLU) fused with GEMM2 ------
// block = 384 threads = NPB nodes x (4 edge-groups x 24 float4-lanes)
__global__ __launch_bounds__(384) void k_agg1(const float* __restrict__ h1,
                                              const float2* __restrict__ sorted,
                                              const int* __restrict__ off,
                                              const float* __restrict__ dinvf,
                                              const float* __restrict__ b1,
                                              const float* __restrict__ W2,
                                              float* __restrict__ h2, int n) {
    __shared__ float  w2s[HIDC * HIDC];
    __shared__ float4 red[NPB][4][24];
    __shared__ float  zrow[NPB][96];
    int t = threadIdx.x;
    for (int i = t; i < HIDC * HIDC; i += 384) w2s[i] = W2[i];
    int nl = t / 96, tn = t % 96;
    int nidx = blockIdx.x * NPB + nl;
    int eg = tn / 24, c4 = tn % 24;
    int ch0 = c4 * 4;
    int v = ch0 >> 5;
    bool valid = nidx < n;
    float4 acc = make_float4(0.f, 0.f, 0.f, 0.f);
    if (valid) {
        int p0 = off[nidx], p1 = off[nidx + 1];
        int p = p0 + eg;
        for (; p + 4 < p1; p += 8) {
            float2 pk0 = sorted[p];
            float2 pk1 = sorted[p + 4];
            unsigned q0 = __float_as_uint(pk0.y), q1 = __float_as_uint(pk1.y);
            int s0 = q0 & 0x3FFFFFFF, s1 = q1 & 0x3FFFFFFF;
            float k0 = (v == 0) ? 1.f : (float)((q0 >> (29 + v)) & 1u);
            float k1 = (v == 0) ? 1.f : (float)((q1 >> (29 + v)) & 1u);
            float nw0 = pk0.x * k0 * dinvf[s0 * 4 + v];
            float nw1 = pk1.x * k1 * dinvf[s1 * 4 + v];
            float4 g0 = *(const float4*)&h1[(size_t)s0 * 96 + ch0];
            float4 g1 = *(const float4*)&h1[(size_t)s1 * 96 + ch0];
            acc.x += g0.x * nw0 + g1.x * nw1;
            acc.y += g0.y * nw0 + g1.y * nw1;
            acc.z += g0.z * nw0 + g1.z * nw1;
            acc.w += g0.w * nw0 + g1.w * nw1;
        }
        if (p < p1) {
            float2 pk = sorted[p];
            unsigned q = __float_as_uint(pk.y);
            int s = q & 0x3FFFFFFF;
            float kk = (v == 0) ? 1.f : (float)((q >> (29 + v)) & 1u);
            float nw = pk.x * kk * dinvf[s * 4 + v];
            float4 g = *(const float4*)&h1[(size_t)s * 96 + ch0];
            acc.x += g.x * nw; acc.y += g.y * nw;
            acc.z += g.z * nw; acc.w += g.w * nw;
        }
    }
    red[nl][eg][c4] = acc;
    __syncthreads();
    if (eg == 0 && valid) {
        float4 r0 = red[nl][0][c4], r1 = red[nl][1][c4];
        float4 r2 = red[nl][2][c4], r3 = red[nl][3][c4];
        float dvv = dinvf[nidx * 4 + v];
        float4 hs = *(const float4*)&h1[(size_t)nidx * 96 + ch0];
        float4 bb = *(const float4*)&b1[ch0 & 31];
        float4 z;
        z.x = fmaxf((r0.x + r1.x + r2.x + r3.x + hs.x * dvv) * dvv + bb.x, 0.f);
        z.y = fmaxf((r0.y + r1.y + r2.y + r3.y + hs.y * dvv) * dvv + bb.y, 0.f);
        z.z = fmaxf((r0.z + r1.z + r2.z + r3.z + hs.z * dvv) * dvv + bb.z, 0.f);
        z.w = fmaxf((r0.w + r1.w + r2.w + r3.w + hs.w * dvv) * dvv + bb.w, 0.f);
        *(float4*)&zrow[nl][ch0] = z;
    }
    __syncthreads();
    if (valid) {
        int j = tn & 31, v2 = tn >> 5;
        float sum = 0.f;
        #pragma unroll
        for (int k = 0; k < HIDC; k++) sum += zrow[nl][v2 * 32 + k] * w2s[k * 32 + j];
        h2[(size_t)nidx * 96 + tn] = sum;
    }
}

// ------- layer2 aggregation (+self loop, +b2, ReLU) → de-interleaved out --
__global__ __launch_bounds__(384) void k_agg2(const float* __restrict__ h2,
                                              const float2* __restrict__ sorted,
                                              const int* __restrict__ off,
                                              const float* __restrict__ dinvf,
                                              const float* __restrict__ b2,
                                              float* __restrict__ out, int n) {
    __shared__ float4 red[NPB][4][24];
    int t = threadIdx.x;
    int nl = t / 96, tn = t % 96;
    int nidx = blockIdx.x * NPB + nl;
    int eg = tn / 24, c4 = tn % 24;
    int ch0 = c4 * 4;
    int v = ch0 >> 5;
    bool valid = nidx < n;
    float4 acc = make_float4(0.f, 0.f, 0.f, 0.f);
    if (valid) {
        int p0 = off[nidx], p1 = off[nidx + 1];
        int p = p0 + eg;
        for (; p + 4 < p1; p += 8) {
            float2 pk0 = sorted[p];
            float2 pk1 = sorted[p + 4];
            unsigned q0 = __float_as_uint(pk0.y), q1 = __float_as_uint(pk1.y);
            int s0 = q0 & 0x3FFFFFFF, s1 = q1 & 0x3FFFFFFF;
            float k0 = (v == 0) ? 1.f : (float)((q0 >> (29 + v)) & 1u);
            float k1 = (v == 0) ? 1.f : (float)((q1 >> (29 + v)) & 1u);
            float nw0 = pk0.x * k0 * dinvf[s0 * 4 + v];
            float nw1 = pk1.x * k1 * dinvf[s1 * 4 + v];
            float4 g0 = *(const float4*)&h2[(size_t)s0 * 96 + ch0];
            float4 g1 = *(const float4*)&h2[(size_t)s1 * 96 + ch0];
            acc.x += g0.x * nw0 + g1.x * nw1;
            acc.y += g0.y * nw0 + g1.y * nw1;
            acc.z += g0.z * nw0 + g1.z * nw1;
            acc.w += g0.w * nw0 + g1.w * nw1;
        }
        if (p < p1) {
            float2 pk = sorted[p];
            unsigned q = __float_as_uint(pk.y);
            int s = q & 0x3FFFFFFF;
            float kk = (v == 0) ? 1.f : (float)((q >> (29 + v)) & 1u);
            float nw = pk.x * kk * dinvf[s * 4 + v];
            float4 g = *(const float4*)&h2[(size_t)s * 96 + ch0];
            acc.x += g.x * nw; acc.y += g.y * nw;
            acc.z += g.z * nw; acc.w += g.w * nw;
        }
    }
    red[nl][eg][c4] = acc;
    __syncthreads();
    if (eg == 0 && valid) {
        float4 r0 = red[nl][0][c4], r1 = red[nl][1][c4];
        float4 r2 = red[nl][2][c4], r3 = red[nl][3][c4];
        float dvv = dinvf[nidx * 4 + v];
        float4 hs = *(const float4*)&h2[(size_t)nidx * 96 + ch0];
        float4 bb = *(const float4*)&b2[ch0 & 31];
        float4 z;
        z.x = fmaxf((r0.x + r1.x + r2.x + r3.x + hs.x * dvv) * dvv + bb.x, 0.f);
        z.y = fmaxf((r0.y + r1.y + r2.y + r3.y + hs.y * dvv) * dvv + bb.y, 0.f);
        z.z = fmaxf((r0.z + r1.z + r2.z + r3.z + hs.z * dvv) * dvv + bb.z, 0.f);
        z.w = fmaxf((r0.w + r1.w + r2.w + r3.w + hs.w * dvv) * dvv + bb.w, 0.f);
        *(float4*)&out[((size_t)v * n + nidx) * HIDC + (ch0 & 31)] = z;
    }
}

// ---------------- GEMM1: h1 = x (N x 512) @ Wc (512 x 96) ----------------
// BM=128, BK=32, 256 threads (4 waves), thread tile 4 rows x 12 cols
__global__ __launch_bounds__(256) void k_gemm1(const float* __restrict__ x,
                                               const float* __restrict__ Wc,
                                               float* __restrict__ h1, int n) {
    __shared__ float xs[32][132];   // k-major, padded
    __shared__ float wsd[32][96];
    int tid = threadIdx.x;
    int m0 = blockIdx.x * 128;
    int rg = tid & 31;   // rows rg*4 .. rg*4+3
    int cg = tid >> 5;   // cols cg*12 .. cg*12+11
    float acc[4][12] = {};
    for (int kt = 0; kt < F_DIMC; kt += 32) {
        for (int i = tid; i < 1024; i += 256) {
            int r = i >> 3, kc = i & 7;
            float4 v = make_float4(0.f, 0.f, 0.f, 0.f);
            int row = m0 + r;
            if (row < n) v = *(const float4*)&x[(size_t)row * F_DIMC + kt + kc * 4];
            xs[kc * 4 + 0][r] = v.x;
            xs[kc * 4 + 1][r] = v.y;
            xs[kc * 4 + 2][r] = v.z;
            xs[kc * 4 + 3][r] = v.w;
        }
        for (int i = tid; i < 768; i += 256) {
            int k = i / 24, c4 = i % 24;
            *(float4*)&wsd[k][c4 * 4] = *(const float4*)&Wc[(size_t)(kt + k) * 96 + c4 * 4];
        }
        __syncthreads();
        #pragma unroll 8
        for (int k = 0; k < 32; k++) {
            float a[4], b[12];
            *(float4*)&a[0] = *(float4*)&xs[k][rg * 4];
            *(float4*)&b[0] = *(float4*)&wsd[k][cg * 12];
            *(float4*)&b[4] = *(float4*)&wsd[k][cg * 12 + 4];
            *(float4*)&b[8] = *(float4*)&wsd[k][cg * 12 + 8];
            #pragma unroll
            for (int i = 0; i < 4; i++) {
                #pragma unroll
                for (int j = 0; j < 12; j++) acc[i][j] += a[i] * b[j];
            }
        }
        __syncthreads();
    }
    #pragma unroll
    for (int i = 0; i < 4; i++) {
        int row = m0 + rg * 4 + i;
        if (row < n) {
            float* dst = &h1[(size_t)row * 96 + cg * 12];
            *(float4*)&dst[0] = make_float4(acc[i][0], acc[i][1], acc[i][2], acc[i][3]);
            *(float4*)&dst[4] = make_float4(acc[i][4], acc[i][5], acc[i][6], acc[i][7]);
            *(float4*)&dst[8] = make_float4(acc[i][8], acc[i][9], acc[i][10], acc[i][11]);
        }
    }
}

extern "C" void kernel_launch(void* const* d_in, const int* in_sizes, int n_in,
                              void* d_out, int out_size, void* d_ws, size_t ws_size,
                              hipStream_t stream) {
    const float* x   = (const float*)d_in[0];
    const int*   ei  = (const int*)d_in[1];     // harness stages integers as int32
    const float* ew  = (const float*)d_in[2];
    const float* m1  = (const float*)d_in[3];
    const float* m2  = (const float*)d_in[4];
    const float* fm1 = (const float*)d_in[5];
    const float* fm2 = (const float*)d_in[6];
    const float* W1  = (const float*)d_in[7];
    const float* b1  = (const float*)d_in[8];
    const float* W2  = (const float*)d_in[9];
    const float* b2  = (const float*)d_in[10];
    float* out = (float*)d_out;
    int Nn = in_sizes[0] / F_DIMC;
    int Ee = in_sizes[2];
    (void)n_in; (void)out_size; (void)ws_size;

    char* ws = (char*)d_ws;
    size_t o = 0;
    auto carve = [&](size_t bytes) -> char* {
        char* p = ws + o;
        o = (o + bytes + 255) & ~(size_t)255;
        return p;
    };
    int*    cnt    = (int*)   carve((size_t)Nn * 4);
    int*    off    = (int*)   carve(((size_t)Nn + 1) * 4);
    int*    bsum   = (int*)   carve(256 * 4);
    int*    bex    = (int*)   carve(256 * 4);
    int*    rank   = (int*)   carve((size_t)Ee * 4);
    float4* dinv   = (float4*)carve((size_t)Nn * 16);         // rsqrt(deg+1), 3 views
    float2* sorted = (float2*)carve((size_t)Ee * 8);          // {w, src|maskbits}
    float*  h1     = (float*) carve((size_t)Nn * 96 * 4);
    float*  h2     = (float*) carve((size_t)Nn * 96 * 4);
    float*  Wc     = (float*) carve((size_t)F_DIMC * 96 * 4);

    hipMemsetAsync(cnt, 0, (size_t)Nn * 4, stream);

    k_wc<<<(F_DIMC * HIDC + 255) / 256, 256, 0, stream>>>(W1, fm1, fm2, Wc);
    k_count<<<(Ee + 255) / 256, 256, 0, stream>>>(ei + Ee, cnt, rank, Ee);
    int nb = (Nn + 1023) / 1024;
    k_scan1<<<nb, 256, 0, stream>>>(cnt, off, bsum, Nn);
    k_scan2<<<1, 256, 0, stream>>>(bsum, bex, nb);
    k_scan3<<<nb, 256, 0, stream>>>(off, bex, Nn);
    k_fill<<<(Ee + 255) / 256, 256, 0, stream>>>(ei, ew, m1, m2, off, rank, sorted, Ee);
    k_deg<<<(Nn * 4 + 255) / 256, 256, 0, stream>>>(sorted, off, dinv, Nn);
    k_gemm1<<<(Nn + 127) / 128, 256, 0, stream>>>(x, Wc, h1, Nn);
    k_agg1<<<(Nn + NPB - 1) / NPB, 384, 0, stream>>>(h1, sorted, off, (const float*)dinv,
                                                     b1, W2, h2, Nn);
    k_agg2<<<(Nn + NPB - 1) / NPB, 384, 0, stream>>>(h2, sorted, off, (const float*)dinv,
                                                     b2, out, Nn);
}